// Round 7
// baseline (558.112 us; speedup 1.0000x reference)
//
#include <hip/hip_runtime.h>
#include <hip/hip_bf16.h>

#define B_   16
#define DF_  1536
#define D_   1024
#define V_   6890
#define PD_  256
#define HID_ 512
#define C_   133
#define VPAD 6912   // 54 * 128
#define CPAD 144    // 9 * 16
#define NBLK 256    // k_chain grid size (co-resident on 256 CUs)

typedef short  short8  __attribute__((ext_vector_type(8)));
typedef float  float4_ __attribute__((ext_vector_type(4)));
typedef double double4_ __attribute__((ext_vector_type(4)));
typedef unsigned short ushort_t;

#define MFMA16   __builtin_amdgcn_mfma_f32_16x16x32_bf16
#define MFMAF64  __builtin_amdgcn_mfma_f64_16x16x4f64

__device__ __forceinline__ float b2f(ushort_t u) {
  union { unsigned int i; float f; } x;
  x.i = ((unsigned int)u) << 16;
  return x.f;
}
__device__ __forceinline__ ushort_t f2b(float f) {
  union { float f; unsigned int i; } x;
  x.f = f;
  unsigned int r = (x.i + 0x7fffu + ((x.i >> 16) & 1u)) >> 16;
  return (ushort_t)r;
}
__device__ __forceinline__ unsigned int f22u(float h0, float h1) {
  __hip_bfloat162 hb = __float22bfloat162_rn(make_float2(h0, h1));
  unsigned int u;
  __builtin_memcpy(&u, &hb, sizeof(u));
  return u;
}

// ---- device-scope grid barrier (all NBLK blocks co-resident: 0 LDS, <=256 VGPR)
__device__ __forceinline__ void gbar(int* bar, int idx) {
  __syncthreads();
  if (threadIdx.x == 0) {
    __threadfence();   // release: wb dirty L2 (agent scope)
    __hip_atomic_fetch_add(&bar[idx], 1, __ATOMIC_ACQ_REL, __HIP_MEMORY_SCOPE_AGENT);
    while (__hip_atomic_load(&bar[idx], __ATOMIC_ACQUIRE, __HIP_MEMORY_SCOPE_AGENT) < NBLK)
      __builtin_amdgcn_s_sleep(8);
    __threadfence();   // acquire: invalidate L1/L2 before block reads others' data
  }
  __syncthreads();
}

// ---- one 16(batch) x 16(col) f64 MFMA tile of out = A[16][K] @ W[K][N]
// m = lane&15 (col within tile AND batch-row for A), kq = lane>>4.
// ncol is the already-clamped absolute column index for W.
template <typename AT>
__device__ __forceinline__ double4_ gemv_tile(const AT* __restrict__ A, int K,
                                              const float* __restrict__ W, int N,
                                              int ncol, int m, int kq) {
  double4_ a0 = {0., 0., 0., 0.}, a1 = a0, a2 = a0, a3 = a0;
  const AT*    ap = A + m * K + kq;
  const float* wp = W + (size_t)kq * N + ncol;
  int nk = K >> 2;
#pragma unroll 2
  for (int t = 0; t < nk; t += 4) {
    a0 = MFMAF64((double)ap[4 * t],      (double)wp[(size_t)(4 * t) * N],      a0, 0, 0, 0);
    a1 = MFMAF64((double)ap[4 * t + 4],  (double)wp[(size_t)(4 * t + 4) * N],  a1, 0, 0, 0);
    a2 = MFMAF64((double)ap[4 * t + 8],  (double)wp[(size_t)(4 * t + 8) * N],  a2, 0, 0, 0);
    a3 = MFMAF64((double)ap[4 * t + 12], (double)wp[(size_t)(4 * t + 12) * N], a3, 0, 0, 0);
  }
  return a0 + a1 + a2 + a3;
}

// ---- pproj block-job: PP[v-tile 64][k_out-tile 64] = PB @ WbT^T (bf16 MFMA)
__device__ __forceinline__ void pproj_job(int jid, int tid,
                                          const ushort_t* __restrict__ PB,
                                          const ushort_t* __restrict__ WbT,
                                          ushort_t* __restrict__ PP) {
  int vt = jid % 108, nt = jid / 108;
  int wave = tid >> 6, lane = tid & 63;
  int q = lane >> 4, l15 = lane & 15;
  int m0 = vt * 64 + wave * 16;
  int n0 = nt * 64;
  int vc = m0 + l15; vc = vc < V_ ? vc : V_ - 1;
  const ushort_t* pb = PB + (size_t)vc * PD_;
  float4_ acc[4] = {};
#pragma unroll 2
  for (int kt = 0; kt < 8; ++kt) {
    int jb = kt * 32 + q * 8;
    short8 a = *(const short8*)(pb + jb);
#pragma unroll
    for (int nf = 0; nf < 4; ++nf) {
      short8 bfr = *(const short8*)(WbT + (size_t)(n0 + nf * 16 + l15) * PD_ + jb);
      acc[nf] = MFMA16(a, bfr, acc[nf], 0, 0, 0);
    }
  }
  int v0w = m0 + q * 4;
#pragma unroll
  for (int nf = 0; nf < 4; ++nf)
#pragma unroll
    for (int r = 0; r < 4; ++r)
      PP[(size_t)(v0w + r) * HID_ + (n0 + nf * 16 + l15)] = f2b(acc[nf][r]);
}

// ---- the fused chain: prep + gemv1..4 (f64 MFMA) + pproj + cont -------------
__global__ void k_chain(const float* __restrict__ features,
                        const float* __restrict__ Wc,  const float* __restrict__ bc,
                        const float* __restrict__ Wv_, const float* __restrict__ Wo_,
                        const float* __restrict__ Wcls, const float* __restrict__ bcls,
                        const float* __restrict__ pos, const float* __restrict__ Wft1,
                        const float* __restrict__ bft1, const float* __restrict__ Wft2,
                        double* __restrict__ part, double* __restrict__ vv,
                        double* __restrict__ att, float* __restrict__ attpj,
                        unsigned char* __restrict__ maskb, float* __restrict__ out0,
                        ushort_t* __restrict__ WT, ushort_t* __restrict__ WbT,
                        ushort_t* __restrict__ PB, ushort_t* __restrict__ PP,
                        int* __restrict__ bar) {
  int tid = threadIdx.x, blk = blockIdx.x;
  int lane = tid & 63, wv = tid >> 6;
  int gw = blk * 4 + wv;
  int m = lane & 15, kq = lane >> 4;

  // ===== Stage A: gemv1 (part = features@W_contact + b) on blocks 0..15;
  //                prep (WT/WbT/PB) on blocks 16..255 =====
  if (blk < 16) {
    int n0 = gw * 16;                                   // 0..1008
    double4_ acc = gemv_tile(features, DF_, Wc, D_, n0 + m, m, kq);
#pragma unroll
    for (int r = 0; r < 4; ++r)
      part[(kq * 4 + r) * D_ + n0 + m] = acc[r] + (double)bc[n0 + m];
  } else {
    const int TOT = CPAD * HID_ + HID_ * PD_ + V_ * PD_;
    for (int i = (blk - 16) * 256 + tid; i < TOT; i += 240 * 256) {
      int u = i;
      if (u < CPAD * HID_) {
        int c = u >> 9, k = u & (HID_ - 1);
        WT[u] = (c < C_) ? f2b(Wft2[(size_t)k * C_ + c]) : (ushort_t)0;
      } else if ((u -= CPAD * HID_) < HID_ * PD_) {
        int k = u & (HID_ - 1), pd = u >> 9;
        WbT[(size_t)k * PD_ + pd] = f2b(Wft1[(size_t)(D_ + pd) * HID_ + k]);
      } else {
        u -= HID_ * PD_;
        PB[u] = f2b(pos[u]);
      }
    }
  }
  gbar(bar, 0);

  // ===== Stage B: gemv2 (vv = part@Wv) blocks 0..15; pproj jobs 0..431 =====
  if (blk < 16) {
    int n0 = gw * 16;
    double4_ acc = gemv_tile(part, D_, Wv_, D_, n0 + m, m, kq);
#pragma unroll
    for (int r = 0; r < 4; ++r) vv[(kq * 4 + r) * D_ + n0 + m] = acc[r];
  } else {
#pragma unroll
    for (int r = 0; r < 2; ++r) {
      int jid = (blk - 16) + 240 * r;
      if (jid < 432) pproj_job(jid, tid, PB, WbT, PP);
    }
  }
  gbar(bar, 1);

  // ===== Stage C: gemv3 (att = vv@Wo) blocks 0..15; pproj jobs 432..863 =====
  if (blk < 16) {
    int n0 = gw * 16;
    double4_ acc = gemv_tile(vv, D_, Wo_, D_, n0 + m, m, kq);
#pragma unroll
    for (int r = 0; r < 4; ++r) att[(kq * 4 + r) * D_ + n0 + m] = acc[r];
  } else {
#pragma unroll
    for (int r = 0; r < 2; ++r) {
      int jid = 432 + (blk - 16) + 240 * r;
      if (jid < 864) pproj_job(jid, tid, PB, WbT, PP);
    }
  }
  gbar(bar, 2);

  // ===== Stage D: gemv4 (attpj = att@W_ft1_top + b_ft1) blocks 0..7;
  //       Stage E: cont (s = att@W_cls + b_cls, f64) waves of blocks 8..115 =====
  if (blk < 8) {
    int n0 = gw * 16;                                   // 0..496
    double4_ acc = gemv_tile(att, D_, Wft1, HID_, n0 + m, m, kq);
#pragma unroll
    for (int r = 0; r < 4; ++r)
      attpj[(kq * 4 + r) * HID_ + n0 + m] = (float)(acc[r] + (double)bft1[n0 + m]);
  } else {
    int t = (blk - 8) * 4 + wv;                         // wave-level tile id
    if (t < 432) {
      int v0 = t * 16;
      int vcl = v0 + m; vcl = vcl < V_ ? vcl : V_ - 1;
      double4_ acc = gemv_tile(att, D_, Wcls, V_, vcl, m, kq);
      int v = v0 + m;
#pragma unroll
      for (int r = 0; r < 4; ++r) {
        int b = kq * 4 + r;
        if (v < V_) {
          double s = acc[r] + (double)bcls[v];
          maskb[b * V_ + v] = (s > 0.0) ? 1 : 0;
          out0[b * V_ + v] = (float)(1.0 / (1.0 + exp(-s)));
        }
      }
    }
  }
}

// ---- main GEMM: preds^T[b] = W_ft2^T @ relu(attproj[b] + PP^T) --------------
// grid (108, 8): v-tile 64, batch pair; swt stride 40 (conflict-free b128).
__global__ __launch_bounds__(256, 3) void k_main(const ushort_t* __restrict__ WT,
                                                 const ushort_t* __restrict__ PP,
                                                 const float* __restrict__ attproj,
                                                 const unsigned char* __restrict__ maskb,
                                                 const float* __restrict__ bft2,
                                                 float* __restrict__ out1) {
  __shared__ ushort_t swt[2][CPAD * 40];   // stride 40 shorts = 80 B -> 2-way max
  __shared__ float attp[2][HID_];
  int b0 = blockIdx.y * 2;
  int wave = threadIdx.x >> 6, lane = threadIdx.x & 63;
  int q = lane >> 4, l15 = lane & 15;
  int vbase = blockIdx.x * 64 + wave * 16;

  for (int i = threadIdx.x; i < 2 * HID_; i += 256)
    attp[i >> 9][i & (HID_ - 1)] = attproj[(b0 + (i >> 9)) * HID_ + (i & (HID_ - 1))];

  auto stage = [&](int kt, int buf) {
#pragma unroll
    for (int ii = 0; ii < 3; ++ii) {
      int i = ii * 256 + threadIdx.x;
      if (i < 576) {
        int row = i >> 2, seg = i & 3;
        *(short8*)&swt[buf][row * 40 + seg * 8] =
            *(const short8*)(WT + (size_t)row * HID_ + kt * 32 + seg * 8);
      }
    }
  };
  stage(0, 0);
  const ushort_t* pbase = PP + (size_t)(vbase + l15) * HID_;
  short8 pcur = *(const short8*)(pbase + q * 8);
  __syncthreads();

  float4_ acc[2][9] = {};
  for (int kt = 0; kt < 16; ++kt) {
    int buf = kt & 1, kb = kt * 32 + q * 8;
    if (kt < 15) stage(kt + 1, buf ^ 1);
    short8 pnext = pcur;
    if (kt < 15) pnext = *(const short8*)(pbase + kb + 32);
    float pf[8];
#pragma unroll
    for (int jj = 0; jj < 8; ++jj) pf[jj] = b2f((ushort_t)pcur[jj]);
    short8 bfr[2];
#pragma unroll
    for (int bb = 0; bb < 2; ++bb) {
      unsigned int uu[4];
#pragma unroll
      for (int jj = 0; jj < 8; jj += 2) {
        float h0 = attp[bb][kb + jj]     + pf[jj];
        float h1 = attp[bb][kb + jj + 1] + pf[jj + 1];
        h0 = h0 > 0.f ? h0 : 0.f;
        h1 = h1 > 0.f ? h1 : 0.f;
        uu[jj >> 1] = f22u(h0, h1);
      }
      __builtin_memcpy(&bfr[bb], uu, 16);
    }
#pragma unroll
    for (int mt = 0; mt < 9; ++mt) {
      short8 a = *(const short8*)&swt[buf][(mt * 16 + l15) * 40 + q * 8];
      acc[0][mt] = MFMA16(a, bfr[0], acc[0][mt], 0, 0, 0);
      acc[1][mt] = MFMA16(a, bfr[1], acc[1][mt], 0, 0, 0);
    }
    pcur = pnext;
    __syncthreads();
  }

  int n = vbase + l15;
  int ncl = n < V_ ? n : V_ - 1;
  bool mk[2];
  mk[0] = (n < V_) && (maskb[(b0 + 0) * V_ + ncl] != 0);
  mk[1] = (n < V_) && (maskb[(b0 + 1) * V_ + ncl] != 0);
#pragma unroll
  for (int bb = 0; bb < 2; ++bb) {
    float* ob = out1 + (size_t)(b0 + bb) * C_ * V_;
#pragma unroll
    for (int mt = 0; mt < 9; ++mt)
#pragma unroll
      for (int r = 0; r < 4; ++r) {
        int c = mt * 16 + q * 4 + r;
        if (c < C_ && n < V_) {
          float val = mk[bb] ? acc[bb][mt][r] + bft2[c] : 0.f;
          ob[(size_t)c * V_ + n] = val;
        }
      }
  }
}

extern "C" void kernel_launch(void* const* d_in, const int* in_sizes, int n_in,
                              void* d_out, int out_size, void* d_ws, size_t ws_size,
                              hipStream_t stream) {
  const float* features  = (const float*)d_in[0];
  // W_scene/b_scene/Wq/Wk dead: softmax over a length-1 sequence == 1.
  const float* W_contact = (const float*)d_in[3];
  const float* b_contact = (const float*)d_in[4];
  const float* Wv        = (const float*)d_in[7];
  const float* Wo        = (const float*)d_in[8];
  const float* W_cls     = (const float*)d_in[9];
  const float* b_cls     = (const float*)d_in[10];
  const float* pos_emb   = (const float*)d_in[11];
  const float* W_ft1     = (const float*)d_in[12];
  const float* b_ft1     = (const float*)d_in[13];
  const float* W_ft2     = (const float*)d_in[14];
  const float* b_ft2     = (const float*)d_in[15];

  char* ws = (char*)d_ws;
  double*        part  = (double*)(ws);                  // 131072
  double*        vv    = (double*)(ws + 131072);         // 131072
  double*        att   = (double*)(ws + 262144);         // 131072
  float*         attpj = (float*)(ws + 393216);          //  32768
  unsigned char* maskb = (unsigned char*)(ws + 425984);  // 110240 (pad->536576)
  ushort_t*      wt    = (ushort_t*)(ws + 536576);       // 147456
  ushort_t*      wbt   = (ushort_t*)(ws + 684032);       // 262144
  ushort_t*      pb    = (ushort_t*)(ws + 946176);       // 3527680
  ushort_t*      pp    = (ushort_t*)(ws + 4473856);      // 7077888
  int*           bar   = (int*)(ws + 11551744);          // 128  -> ~11.55 MB

  float* out0 = (float*)d_out;
  float* out1 = out0 + (size_t)B_ * V_;

  hipMemsetAsync(bar, 0, 128, stream);
  k_chain<<<NBLK, 256, 0, stream>>>(features, W_contact, b_contact, Wv, Wo,
                                    W_cls, b_cls, pos_emb, W_ft1, b_ft1, W_ft2,
                                    part, vv, att, attpj, maskb, out0,
                                    wt, wbt, pb, pp, bar);
  k_main<<<dim3(108, 8), 256, 0, stream>>>(wt, pp, attpj, maskb, b_ft2, out1);
}